// Round 3
// baseline (2490.143 us; speedup 1.0000x reference)
//
#include <hip/hip_runtime.h>

#define NV    50000
#define NRAD  5
#define NANG  8
#define FEAT  64
#define NTPL  64
#define NXY   (NRAD*NANG)      // 40
#define KDIM  (NXY*FEAT)       // 2560

#define TM 64
#define TN 128
#define BLK 256

// W2[(xy*64+f)*N + (o*64+t)] = sum_{r,a} kern[r,a,x,y] * NW[t, r, (a+o*delta)%8, f]
__global__ void build_w2_kernel(const float* __restrict__ kern,
                                const float* __restrict__ nw,
                                const int* __restrict__ deltap,
                                float* __restrict__ w2,
                                int N) {
    int p = blockIdx.x * blockDim.x + threadIdx.x;
    int total = KDIM * N;
    if (p >= total) return;
    int n  = p % N;          // n = o*64 + t
    int kd = p / N;          // kd = xy*64 + f
    int t  = n % NTPL;
    int o  = n / NTPL;
    int f  = kd % FEAT;
    int xy = kd / FEAT;
    int x  = xy / NANG;
    int y  = xy % NANG;
    int delta = deltap[0];
    int ob = o * delta;
    float acc = 0.f;
#pragma unroll
    for (int r = 0; r < NRAD; ++r) {
#pragma unroll
        for (int a = 0; a < NANG; ++a) {
            int a2 = (a + ob) & (NANG - 1);
            acc += kern[((r*NANG + a)*NRAD + x)*NANG + y]
                 * nw[((t*NRAD + r)*NANG + a2)*FEAT + f];
        }
    }
    w2[p] = acc;
}

__launch_bounds__(BLK, 3)
__global__ void conv_main_kernel(const float* __restrict__ mesh,
                                 const int* __restrict__ bidx,
                                 const float* __restrict__ bw,
                                 const float* __restrict__ w2,
                                 const float* __restrict__ sw,
                                 const float* __restrict__ bias,
                                 float* __restrict__ out,
                                 int N, int nvt) {
    __shared__ float sA[FEAT][TM + 4];   // [f][vertex]  (transposed interp tile)
    __shared__ float sB[FEAT][TN + 4];   // [f][n_local] (W2 tile; also SW^T in phase 0)

    const int tid = threadIdx.x;

    // ---- XCD-pinned decomposition of the flat grid ----
    // Empirically blockIdx round-robins across the 8 XCDs (flat % 8).
    // Pin N-slice `ntile` to XCD pair (ntile = xcd>>1) so each XCD's 4 MB L2
    // holds exactly ONE 1.31 MB W2 slice instead of all four (5.24 MB) + mesh.
    // Bijective for NT==4 and even nvt: flat = 8q+x -> ntile=x>>1, vt=2q+(x&1).
    const int NT = N / TN;
    int flat = blockIdx.x;
    int ntile, vt;
    if (NT == 4 && (nvt & 1) == 0) {
        ntile = (flat & 7) >> 1;
        vt    = ((flat >> 3) << 1) | (flat & 1);
    } else {
        ntile = flat % NT;
        vt    = flat / NT;
    }
    const int n0 = ntile * TN;
    const int k0 = vt * TM;

    const int tn = tid & 31;             // col group: cols tn*4 .. tn*4+3
    const int mg = tid >> 5;             // row group: rows mg*8 .. mg*8+7

    const int vS = tid & 63;             // staging: vertex handled by this thread
    const int fS = (tid >> 6) * 16;      // staging: feature chunk start

    float acc[8][4];

    int tcol[4];
#pragma unroll
    for (int j = 0; j < 4; ++j) tcol[j] = (n0 + tn*4 + j) % NTPL;

    // ---------------- phase 0: acc = bias + center (SW @ mesh_row) ----------------
    {
        // stage SW transposed into sB storage: swl[f*64 + t]
        float* swl = &sB[0][0];
#pragma unroll
        for (int c = 0; c < 16; ++c) {
            int e = tid * 16 + c;            // e = t*64 + f, covers 4096
            int t = e >> 6;
            int f = e & 63;
            swl[f * NTPL + t] = sw[e];
        }
        // stage this block's mesh rows transposed into sA[f][v]
        {
            int k = k0 + vS; if (k >= NV) k = NV - 1;
            const float4* src = (const float4*)(mesh + (long)k * FEAT + fS);
#pragma unroll
            for (int c = 0; c < 4; ++c) {
                float4 mv = src[c];
                sA[fS + 4*c + 0][vS] = mv.x;
                sA[fS + 4*c + 1][vS] = mv.y;
                sA[fS + 4*c + 2][vS] = mv.z;
                sA[fS + 4*c + 3][vS] = mv.w;
            }
        }
        __syncthreads();

        float bv[4];
#pragma unroll
        for (int j = 0; j < 4; ++j) bv[j] = bias[tcol[j]];
#pragma unroll
        for (int mi = 0; mi < 8; ++mi)
#pragma unroll
            for (int j = 0; j < 4; ++j) acc[mi][j] = bv[j];

        for (int f = 0; f < FEAT; ++f) {
            float wv[4];
#pragma unroll
            for (int j = 0; j < 4; ++j) wv[j] = swl[f * NTPL + tcol[j]];
            float av[8];
#pragma unroll
            for (int mi = 0; mi < 8; ++mi) av[mi] = sA[f][mg*8 + mi];
#pragma unroll
            for (int mi = 0; mi < 8; ++mi)
#pragma unroll
                for (int j = 0; j < 4; ++j)
                    acc[mi][j] += av[mi] * wv[j];
        }
    }

    // ---------------- main loop: 40 xy slices, K-chunk = 64 feats ----------------
    for (int xy = 0; xy < NXY; ++xy) {
        __syncthreads();   // previous phase readers done before restaging

        // stage interp tile -> sA[f][v]:  interp = sum_i w_i * mesh[idx_i]
        {
            int k = k0 + vS; if (k >= NV) k = NV - 1;
            long base = ((long)k * NXY + xy) * 3;
            int   i0 = bidx[base+0], i1 = bidx[base+1], i2 = bidx[base+2];
            float w0 = bw[base+0],   w1 = bw[base+1],   w2v = bw[base+2];
            const float4* p0 = (const float4*)(mesh + (long)i0 * FEAT + fS);
            const float4* p1 = (const float4*)(mesh + (long)i1 * FEAT + fS);
            const float4* p2 = (const float4*)(mesh + (long)i2 * FEAT + fS);
#pragma unroll
            for (int c = 0; c < 4; ++c) {
                float4 a = p0[c], b = p1[c], d = p2[c];
                sA[fS + 4*c + 0][vS] = w0*a.x + w1*b.x + w2v*d.x;
                sA[fS + 4*c + 1][vS] = w0*a.y + w1*b.y + w2v*d.y;
                sA[fS + 4*c + 2][vS] = w0*a.z + w1*b.z + w2v*d.z;
                sA[fS + 4*c + 3][vS] = w0*a.w + w1*b.w + w2v*d.w;
            }
        }
        // stage W2 tile -> sB[f][n_local]
        {
            int r  = tid & 63;           // row (feat within slice)
            int ch = tid >> 6;           // col chunk of 32
            const float* src = w2 + (long)(xy*FEAT + r) * N + n0 + ch*32;
            float* dst = &sB[r][ch*32];
#pragma unroll
            for (int c = 0; c < 8; ++c) {
                ((float4*)dst)[c] = ((const float4*)src)[c];
            }
        }
        __syncthreads();

        // 64 k-steps of 8x4 outer product per thread
#pragma unroll 4
        for (int kk = 0; kk < FEAT; ++kk) {
            float4 alo = *(const float4*)&sA[kk][mg*8 + 0];
            float4 ahi = *(const float4*)&sA[kk][mg*8 + 4];
            float4 b   = *(const float4*)&sB[kk][tn*4];
            float av[8] = {alo.x, alo.y, alo.z, alo.w, ahi.x, ahi.y, ahi.z, ahi.w};
            float bv[4] = {b.x, b.y, b.z, b.w};
#pragma unroll
            for (int mi = 0; mi < 8; ++mi)
#pragma unroll
                for (int j = 0; j < 4; ++j)
                    acc[mi][j] += av[mi] * bv[j];
        }
    }

    // ---------------- epilogue: ReLU + store ----------------
#pragma unroll
    for (int mi = 0; mi < 8; ++mi) {
        int k = k0 + mg*8 + mi;
        if (k < NV) {
            float4 r;
            r.x = fmaxf(acc[mi][0], 0.f);
            r.y = fmaxf(acc[mi][1], 0.f);
            r.z = fmaxf(acc[mi][2], 0.f);
            r.w = fmaxf(acc[mi][3], 0.f);
            *(float4*)(out + (long)k * N + n0 + tn*4) = r;
        }
    }
}

extern "C" void kernel_launch(void* const* d_in, const int* in_sizes, int n_in,
                              void* d_out, int out_size, void* d_ws, size_t ws_size,
                              hipStream_t stream) {
    const float* mesh   = (const float*)d_in[0];
    const int*   bidx   = (const int*)d_in[1];
    const float* bw     = (const float*)d_in[2];
    const float* kern   = (const float*)d_in[3];
    const float* nw     = (const float*)d_in[4];
    const float* sw     = (const float*)d_in[5];
    const float* bias   = (const float*)d_in[6];
    const int*   deltap = (const int*)d_in[7];

    int N = out_size / NV;               // O * 64  (O derived from output size)
    float* w2 = (float*)d_ws;            // KDIM * N floats (5.24 MB at O=8)

    int total = KDIM * N;
    build_w2_kernel<<<(total + 255)/256, 256, 0, stream>>>(kern, nw, deltap, w2, N);

    int nvt = (NV + TM - 1) / TM;        // 782
    int NT  = N / TN;                    // 4
    dim3 grid(NT * nvt);
    conv_main_kernel<<<grid, BLK, 0, stream>>>(mesh, bidx, bw, w2, sw, bias,
                                               (float*)d_out, N, nvt);
}

// Round 5
// 1138.643 us; speedup vs baseline: 2.1869x; 2.1869x over previous
//
#include <hip/hip_runtime.h>

#define NV    50000
#define NRAD  5
#define NANG  8
#define FEAT  64
#define NTPL  64
#define NXY   (NRAD*NANG)      // 40
#define KDIM  (NXY*FEAT)       // 2560
#define KB8   (KDIM/8)         // 320

using short8  = __attribute__((ext_vector_type(8))) short;
using floatx4 = __attribute__((ext_vector_type(4))) float;

__device__ __forceinline__ unsigned short bf16_rne(float x) {
    unsigned u = __builtin_bit_cast(unsigned, x);
    u += 0x7FFFu + ((u >> 16) & 1u);
    return (unsigned short)(u >> 16);
}
__device__ __forceinline__ float bf16f(unsigned short h) {
    unsigned u = ((unsigned)h) << 16;
    return __builtin_bit_cast(float, u);
}

// ---------------------------------------------------------------------------
// Build W2 folded weights in split-bf16, packed in MFMA-B-fragment order:
//   W2[(xy*64+f)][o*64+t] = sum_{r,a} kern[r,a,x,y] * NW[t,r,(a+o*delta)%8,f]
//   stored at w2{hi,lo}[ ((k>>3)*N + n)*8 + (k&7) ]
// ---------------------------------------------------------------------------
__global__ void build_w2p_kernel(const float* __restrict__ kern,
                                 const float* __restrict__ nw,
                                 const int* __restrict__ deltap,
                                 unsigned short* __restrict__ w2hi,
                                 unsigned short* __restrict__ w2lo,
                                 int N) {
    int p = blockIdx.x * blockDim.x + threadIdx.x;
    int total = KDIM * N;
    if (p >= total) return;
    int n  = p % N;          // n = o*64 + t
    int k  = p / N;          // k = xy*64 + f
    int t  = n % NTPL;
    int o  = n / NTPL;
    int f  = k % FEAT;
    int xy = k / FEAT;
    int x  = xy / NANG;
    int y  = xy % NANG;
    int ob = o * deltap[0];
    float acc = 0.f;
#pragma unroll
    for (int r = 0; r < NRAD; ++r) {
#pragma unroll
        for (int a = 0; a < NANG; ++a) {
            int a2 = (a + ob) & (NANG - 1);
            acc += kern[((r*NANG + a)*NRAD + x)*NANG + y]
                 * nw[((t*NRAD + r)*NANG + a2)*FEAT + f];
        }
    }
    unsigned short hi = bf16_rne(acc);
    unsigned short lo = bf16_rne(acc - bf16f(hi));
    long off = ((long)(k >> 3) * N + n) * 8 + (k & 7);
    w2hi[off] = hi;
    w2lo[off] = lo;
}

// ---------------------------------------------------------------------------
// Main kernel: one block = 64 vertices x full N=512 columns.
// 512 threads = 8 waves; wave w owns columns [w*64, w*64+64).
// Per xy slice: stage interp tile (bf16 hi/lo, XOR-swizzled) in LDS once,
// then 3-product split-bf16 MFMA against fragment-packed W2 from global/L2.
// ---------------------------------------------------------------------------
__launch_bounds__(512)
__global__ void conv_mfma_kernel(const float* __restrict__ mesh,
                                 const int* __restrict__ bidx,
                                 const float* __restrict__ bw,
                                 const unsigned short* __restrict__ w2hi,
                                 const unsigned short* __restrict__ w2lo,
                                 const float* __restrict__ sw,
                                 const float* __restrict__ bias,
                                 float* __restrict__ out,
                                 int N) {
    __shared__ __align__(16) unsigned short Ahi[64 * 64];  // [row v][col k] bf16, swizzled
    __shared__ __align__(16) unsigned short Alo[64 * 64];

    const int tid  = threadIdx.x;
    const int lane = tid & 63;
    const int wid  = tid >> 6;           // wave id 0..7 -> column slice
    const int k0   = blockIdx.x * 64;    // vertex base

    const int vS = tid & 63;             // staging: vertex row
    const int fS = (tid >> 6) * 8;       // staging: 8-feature chunk

    const int l15 = lane & 15;
    const int lg  = lane >> 4;           // k-group 0..3

    floatx4 acc[4][4];
#pragma unroll
    for (int mf = 0; mf < 4; ++mf)
#pragma unroll
        for (int nf = 0; nf < 4; ++nf) {
            floatx4 z = {0.f, 0.f, 0.f, 0.f};
            acc[mf][nf] = z;
        }

    // ================= phase 0: center term via MFMA over K=64 feats =========
    {
        // stage this block's mesh rows
        int k = k0 + vS; if (k >= NV) k = NV - 1;
        const floatx4* p = (const floatx4*)(mesh + (long)k * FEAT + fS);
        floatx4 a = p[0], b = p[1];
        short8 H, L;
#pragma unroll
        for (int j = 0; j < 4; ++j) {
            unsigned short hh = bf16_rne(a[j]);
            H[j] = (short)hh;
            L[j] = (short)bf16_rne(a[j] - bf16f(hh));
        }
#pragma unroll
        for (int j = 0; j < 4; ++j) {
            unsigned short hh = bf16_rne(b[j]);
            H[4 + j] = (short)hh;
            L[4 + j] = (short)bf16_rne(b[j] - bf16f(hh));
        }
        int byte = (fS * 2) ^ ((vS & 7) << 4);
        *(short8*)((char*)Ahi + vS * 128 + byte) = H;
        *(short8*)((char*)Alo + vS * 128 + byte) = L;
    }
    __syncthreads();

#pragma unroll
    for (int ks = 0; ks < 2; ++ks) {
        short8 ah[4], al[4];
#pragma unroll
        for (int mf = 0; mf < 4; ++mf) {
            int row = mf * 16 + l15;
            int cb  = (ks * 64 + lg * 16) ^ ((row & 7) << 4);
            ah[mf] = *(const short8*)((const char*)Ahi + row * 128 + cb);
            al[mf] = *(const short8*)((const char*)Alo + row * 128 + cb);
        }
#pragma unroll
        for (int nf = 0; nf < 4; ++nf) {
            int t = nf * 16 + l15;                       // center col == t (indep of wave)
            const floatx4* sp = (const floatx4*)(sw + t * FEAT + ks * 32 + lg * 8);
            floatx4 s0 = sp[0], s1 = sp[1];
            short8 bh, bl;
#pragma unroll
            for (int j = 0; j < 4; ++j) {
                unsigned short hh = bf16_rne(s0[j]);
                bh[j] = (short)hh;
                bl[j] = (short)bf16_rne(s0[j] - bf16f(hh));
            }
#pragma unroll
            for (int j = 0; j < 4; ++j) {
                unsigned short hh = bf16_rne(s1[j]);
                bh[4 + j] = (short)hh;
                bl[4 + j] = (short)bf16_rne(s1[j] - bf16f(hh));
            }
#pragma unroll
            for (int mf = 0; mf < 4; ++mf) {
                acc[mf][nf] = __builtin_amdgcn_mfma_f32_16x16x32_bf16(ah[mf], bh, acc[mf][nf], 0, 0, 0);
                acc[mf][nf] = __builtin_amdgcn_mfma_f32_16x16x32_bf16(ah[mf], bl, acc[mf][nf], 0, 0, 0);
                acc[mf][nf] = __builtin_amdgcn_mfma_f32_16x16x32_bf16(al[mf], bh, acc[mf][nf], 0, 0, 0);
            }
        }
    }

    // bias: col t = nf*16 + l15 (mod 64)
#pragma unroll
    for (int nf = 0; nf < 4; ++nf) {
        float bv = bias[nf * 16 + l15];
#pragma unroll
        for (int mf = 0; mf < 4; ++mf)
#pragma unroll
            for (int r = 0; r < 4; ++r) acc[mf][nf][r] += bv;
    }

    // ================= main loop: 40 xy slices =================
    for (int xy = 0; xy < NXY; ++xy) {
        __syncthreads();   // previous readers done before restaging
        {
            int k = k0 + vS; if (k >= NV) k = NV - 1;
            long base = ((long)k * NXY + xy) * 3;
            int   i0 = bidx[base + 0], i1 = bidx[base + 1], i2 = bidx[base + 2];
            float w0 = bw[base + 0],   w1 = bw[base + 1],   w2v = bw[base + 2];
            const floatx4* p0 = (const floatx4*)(mesh + (long)i0 * FEAT + fS);
            const floatx4* p1 = (const floatx4*)(mesh + (long)i1 * FEAT + fS);
            const floatx4* p2 = (const floatx4*)(mesh + (long)i2 * FEAT + fS);
            short8 H, L;
#pragma unroll
            for (int c = 0; c < 2; ++c) {
                floatx4 a = p0[c], b = p1[c], d = p2[c];
#pragma unroll
                for (int j = 0; j < 4; ++j) {
                    float v = w0 * a[j] + w1 * b[j] + w2v * d[j];
                    unsigned short hh = bf16_rne(v);
                    H[c * 4 + j] = (short)hh;
                    L[c * 4 + j] = (short)bf16_rne(v - bf16f(hh));
                }
            }
            int byte = (fS * 2) ^ ((vS & 7) << 4);
            *(short8*)((char*)Ahi + vS * 128 + byte) = H;
            *(short8*)((char*)Alo + vS * 128 + byte) = L;
        }
        __syncthreads();

#pragma unroll
        for (int ks = 0; ks < 2; ++ks) {
            short8 ah[4], al[4];
#pragma unroll
            for (int mf = 0; mf < 4; ++mf) {
                int row = mf * 16 + l15;
                int cb  = (ks * 64 + lg * 16) ^ ((row & 7) << 4);
                ah[mf] = *(const short8*)((const char*)Ahi + row * 128 + cb);
                al[mf] = *(const short8*)((const char*)Alo + row * 128 + cb);
            }
            int kb = xy * 8 + ks * 4 + lg;               // global k / 8
#pragma unroll
            for (int nf = 0; nf < 4; ++nf) {
                long n   = (long)wid * 64 + nf * 16 + l15;
                long off = ((long)kb * N + n) * 8;
                short8 bh = *(const short8*)(w2hi + off);
                short8 bl = *(const short8*)(w2lo + off);
#pragma unroll
                for (int mf = 0; mf < 4; ++mf) {
                    acc[mf][nf] = __builtin_amdgcn_mfma_f32_16x16x32_bf16(ah[mf], bh, acc[mf][nf], 0, 0, 0);
                    acc[mf][nf] = __builtin_amdgcn_mfma_f32_16x16x32_bf16(ah[mf], bl, acc[mf][nf], 0, 0, 0);
                    acc[mf][nf] = __builtin_amdgcn_mfma_f32_16x16x32_bf16(al[mf], bh, acc[mf][nf], 0, 0, 0);
                }
            }
        }
    }

    // ================= epilogue: ReLU + store =================
    // D frag: row = mf*16 + 4*lg + r, col = wid*64 + nf*16 + l15
#pragma unroll
    for (int mf = 0; mf < 4; ++mf) {
        int row0 = k0 + mf * 16 + lg * 4;
#pragma unroll
        for (int nf = 0; nf < 4; ++nf) {
            long col = (long)wid * 64 + nf * 16 + l15;
            floatx4 d = acc[mf][nf];
#pragma unroll
            for (int r = 0; r < 4; ++r) {
                int row = row0 + r;
                if (row < NV) out[(long)row * N + col] = fmaxf(d[r], 0.f);
            }
        }
    }
}

extern "C" void kernel_launch(void* const* d_in, const int* in_sizes, int n_in,
                              void* d_out, int out_size, void* d_ws, size_t ws_size,
                              hipStream_t stream) {
    const float* mesh   = (const float*)d_in[0];
    const int*   bidx   = (const int*)d_in[1];
    const float* bw     = (const float*)d_in[2];
    const float* kern   = (const float*)d_in[3];
    const float* nw     = (const float*)d_in[4];
    const float* sw     = (const float*)d_in[5];
    const float* bias   = (const float*)d_in[6];
    const int*   deltap = (const int*)d_in[7];

    int N = out_size / NV;                       // 512 for delta=1
    unsigned short* w2hi = (unsigned short*)d_ws;            // KB8*N*8 bf16 = 2.62 MB
    unsigned short* w2lo = w2hi + (long)KB8 * N * 8;         // + 2.62 MB

    int total = KDIM * N;
    build_w2p_kernel<<<(total + 255) / 256, 256, 0, stream>>>(kern, nw, deltap,
                                                              w2hi, w2lo, N);

    int nblocks = (NV + 63) / 64;                // 782
    conv_mfma_kernel<<<nblocks, 512, 0, stream>>>(mesh, bidx, bw, w2hi, w2lo,
                                                  sw, bias, (float*)d_out, N);
}

// Round 7
// 807.028 us; speedup vs baseline: 3.0856x; 1.4109x over previous
//
#include <hip/hip_runtime.h>

#define NV    50000
#define NRAD  5
#define NANG  8
#define FEAT  64
#define NTPL  64
#define NXY   40
#define KDIM  2560

using short8  = __attribute__((ext_vector_type(8))) short;
using floatx4 = __attribute__((ext_vector_type(4))) float;

__device__ __forceinline__ unsigned short bf16_rne(float x) {
    unsigned u = __builtin_bit_cast(unsigned, x);
    u += 0x7FFFu + ((u >> 16) & 1u);
    return (unsigned short)(u >> 16);
}
__device__ __forceinline__ float bf16f(unsigned short h) {
    unsigned u = ((unsigned)h) << 16;
    return __builtin_bit_cast(float, u);
}

// ---------------------------------------------------------------------------
// W2[(xy*64+f)][o*64+t] = sum_{r,a} kern[r,a,x,y] * NW[t,r,(a+o*delta)%8,f]
// packed hi/lo-interleaved in B-fragment order:
//   shorts base = ((k>>3)*N + n)*16 ; hi at base+(k&7), lo at base+8+(k&7)
// Thread map: f fastest -> nw reads coalesced.
// ---------------------------------------------------------------------------
__global__ void build_w2p_kernel(const float* __restrict__ kern,
                                 const float* __restrict__ nw,
                                 const int* __restrict__ deltap,
                                 unsigned short* __restrict__ w2,
                                 int N) {
    int p = blockIdx.x * blockDim.x + threadIdx.x;
    if (p >= KDIM * N) return;
    int f  = p & 63;
    int r2 = p >> 6;          // xy*N + n
    int n  = r2 % N;
    int xy = r2 / N;
    int t  = n & 63;
    int o  = n >> 6;
    int x  = xy / NANG;
    int y  = xy % NANG;
    int ob = o * deltap[0];
    float acc = 0.f;
#pragma unroll
    for (int r = 0; r < NRAD; ++r) {
#pragma unroll
        for (int a = 0; a < NANG; ++a) {
            int a2 = (a + ob) & (NANG - 1);
            acc += kern[((r*NANG + a)*NRAD + x)*NANG + y]
                 * nw[((t*NRAD + r)*NANG + a2)*FEAT + f];
        }
    }
    unsigned short hi = bf16_rne(acc);
    unsigned short lo = bf16_rne(acc - bf16f(hi));
    int k = xy * 64 + f;
    long base = ((long)(k >> 3) * N + n) * 16 + (k & 7);
    w2[base]     = hi;
    w2[base + 8] = lo;
}

// ---------------------------------------------------------------------------
// Main: block = 64 vertices x N=512 cols, 512 threads = 8 waves (64 cols each).
// Double-buffered LDS A-tile; gathers issued one phase ahead; bidx/bw two
// ahead; ONE barrier per xy. MFMA: 16x16x32 bf16 (R5-verified maps),
// split-bf16 3-product (~f32 accuracy).
// LDS row: 256B = 64 bf16 hi [0,128) + 64 bf16 lo [128,256), XOR-swizzled.
// ---------------------------------------------------------------------------
__launch_bounds__(512)
__global__ void conv_mfma_kernel(const float* __restrict__ mesh,
                                 const int* __restrict__ bidx,
                                 const float* __restrict__ bw,
                                 const unsigned short* __restrict__ w2,
                                 const float* __restrict__ sw,
                                 const float* __restrict__ bias,
                                 float* __restrict__ out,
                                 int N) {
    __shared__ __align__(16) unsigned short buf0[64 * 128];  // 16 KB
    __shared__ __align__(16) unsigned short buf1[64 * 128];  // 16 KB

    const int tid  = threadIdx.x;
    const int lane = tid & 63;
    const int wid  = tid >> 6;
    const int k0   = blockIdx.x * 64;

    // staging role: 8 lanes per row (contiguous 256B gathers per row)
    const int srow = (wid << 3) + (lane >> 3);
    const int sfc  = (lane & 7) << 3;
    int grow = k0 + srow; if (grow >= NV) grow = NV - 1;
    const int wbyte = srow * 256 + ((sfc << 1) ^ ((srow & 7) << 4));

    // mfma role (16x16x32, R5-verified)
    const int l15 = lane & 15;
    const int lg  = lane >> 4;            // k-group 0..3
    const int rsw = (l15 & 7) << 4;       // read swizzle (row&7 == l15&7)

    floatx4 acc[4][4];
#pragma unroll
    for (int mf = 0; mf < 4; ++mf)
#pragma unroll
        for (int nf = 0; nf < 4; ++nf) {
            floatx4 z = {0.f, 0.f, 0.f, 0.f};
            acc[mf][nf] = z;
        }

    // ---- helpers ----
    auto cvt_write = [&](float w0, float w1, float w2v,
                         floatx4 a0, floatx4 a1, floatx4 b0, floatx4 b1,
                         floatx4 c0, floatx4 c1, unsigned short* buf) {
        short8 H, L;
#pragma unroll
        for (int j = 0; j < 4; ++j) {
            float v = w0 * a0[j] + w1 * b0[j] + w2v * c0[j];
            unsigned short hh = bf16_rne(v);
            H[j] = (short)hh; L[j] = (short)bf16_rne(v - bf16f(hh));
            float u = w0 * a1[j] + w1 * b1[j] + w2v * c1[j];
            unsigned short uh = bf16_rne(u);
            H[4 + j] = (short)uh; L[4 + j] = (short)bf16_rne(u - bf16f(uh));
        }
        *(short8*)((char*)buf + wbyte)       = H;
        *(short8*)((char*)buf + wbyte + 128) = L;
    };

    auto mfma_phase = [&](const unsigned short* buf, int xy) {
#pragma unroll
        for (int ks = 0; ks < 2; ++ks) {
            short8 ah[4], al[4];
#pragma unroll
            for (int mf = 0; mf < 4; ++mf) {
                int row = mf * 16 + l15;
                int cb  = ((ks << 6) + (lg << 4)) ^ rsw;   // k byte = (ks*32+lg*8)*2
                const char* p = (const char*)buf + row * 256 + cb;
                ah[mf] = *(const short8*)(p);
                al[mf] = *(const short8*)(p + 128);
            }
            long kb = (long)(xy * 8 + (ks << 2) + lg);
            const char* bp = (const char*)w2 + (kb * N + (wid << 6) + l15) * 32;
#pragma unroll
            for (int nf = 0; nf < 4; ++nf) {
                short8 bh = *(const short8*)(bp + nf * 512);
                short8 bl = *(const short8*)(bp + nf * 512 + 16);
                __builtin_amdgcn_s_setprio(1);
#pragma unroll
                for (int mf = 0; mf < 4; ++mf) {
                    acc[mf][nf] = __builtin_amdgcn_mfma_f32_16x16x32_bf16(ah[mf], bh, acc[mf][nf], 0, 0, 0);
                    acc[mf][nf] = __builtin_amdgcn_mfma_f32_16x16x32_bf16(ah[mf], bl, acc[mf][nf], 0, 0, 0);
                    acc[mf][nf] = __builtin_amdgcn_mfma_f32_16x16x32_bf16(al[mf], bh, acc[mf][nf], 0, 0, 0);
                }
                __builtin_amdgcn_s_setprio(0);
            }
        }
    };

    const long qrow = (long)grow * NXY * 3;
    auto load_q = [&](int xy, int& i0, int& i1, int& i2,
                      float& w0, float& w1, float& w2v) {
        int xyc = xy < NXY ? xy : NXY - 1;
        long b = qrow + (long)xyc * 3;
        i0 = bidx[b]; i1 = bidx[b + 1]; i2 = bidx[b + 2];
        w0 = bw[b];   w1 = bw[b + 1];   w2v = bw[b + 2];
    };

    floatx4 g0a, g0b, g1a, g1b, g2a, g2b;
    auto issue_gather = [&](int i0, int i1, int i2) {
        const floatx4* p0 = (const floatx4*)(mesh + (long)i0 * FEAT + sfc);
        g0a = p0[0]; g0b = p0[1];
        const floatx4* p1 = (const floatx4*)(mesh + (long)i1 * FEAT + sfc);
        g1a = p1[0]; g1b = p1[1];
        const floatx4* p2 = (const floatx4*)(mesh + (long)i2 * FEAT + sfc);
        g2a = p2[0]; g2b = p2[1];
    };

    int   iA0, iA1, iA2, iB0, iB1, iB2;
    float wA0, wA1, wA2, wB0, wB1, wB2;

    // ================= prologue =================
    {   // stage own mesh row into buf0 (for center term)
        const floatx4* p = (const floatx4*)(mesh + (long)grow * FEAT + sfc);
        floatx4 a = p[0], b = p[1];
        cvt_write(1.f, 0.f, 0.f, a, b, a, b, a, b, buf0);
    }
    load_q(0, iA0, iA1, iA2, wA0, wA1, wA2);
    load_q(1, iB0, iB1, iB2, wB0, wB1, wB2);
    issue_gather(iA0, iA1, iA2);                 // xy=0, lands during center
    __syncthreads();

    // center term: SW MFMA over K=64 feats (R5-verified structure)
#pragma unroll
    for (int ks = 0; ks < 2; ++ks) {
        short8 ah[4], al[4];
#pragma unroll
        for (int mf = 0; mf < 4; ++mf) {
            int row = mf * 16 + l15;
            int cb  = ((ks << 6) + (lg << 4)) ^ rsw;
            const char* p = (const char*)buf0 + row * 256 + cb;
            ah[mf] = *(const short8*)(p);
            al[mf] = *(const short8*)(p + 128);
        }
#pragma unroll
        for (int nf = 0; nf < 4; ++nf) {
            int t = nf * 16 + l15;
            const floatx4* sp = (const floatx4*)(sw + t * FEAT + (ks << 5) + (lg << 3));
            floatx4 s0 = sp[0], s1 = sp[1];
            short8 bh, bl;
#pragma unroll
            for (int j = 0; j < 4; ++j) {
                unsigned short hh = bf16_rne(s0[j]);
                bh[j] = (short)hh; bl[j] = (short)bf16_rne(s0[j] - bf16f(hh));
                unsigned short uh = bf16_rne(s1[j]);
                bh[4 + j] = (short)uh; bl[4 + j] = (short)bf16_rne(s1[j] - bf16f(uh));
            }
#pragma unroll
            for (int mf = 0; mf < 4; ++mf) {
                acc[mf][nf] = __builtin_amdgcn_mfma_f32_16x16x32_bf16(ah[mf], bh, acc[mf][nf], 0, 0, 0);
                acc[mf][nf] = __builtin_amdgcn_mfma_f32_16x16x32_bf16(ah[mf], bl, acc[mf][nf], 0, 0, 0);
                acc[mf][nf] = __builtin_amdgcn_mfma_f32_16x16x32_bf16(al[mf], bh, acc[mf][nf], 0, 0, 0);
            }
        }
    }
    // bias (col % 64 = nf*16 + l15)
#pragma unroll
    for (int nf = 0; nf < 4; ++nf) {
        float bv = bias[nf * 16 + l15];
#pragma unroll
        for (int mf = 0; mf < 4; ++mf)
#pragma unroll
            for (int r = 0; r < 4; ++r) acc[mf][nf][r] += bv;
    }
    __syncthreads();                             // buf0 free to rewrite

    cvt_write(wA0, wA1, wA2, g0a, g0b, g1a, g1b, g2a, g2b, buf0);  // xy=0
    load_q(2, iA0, iA1, iA2, wA0, wA1, wA2);
    issue_gather(iB0, iB1, iB2);                 // xy=1
    __syncthreads();

    // ================= main loop: 2 xy per iteration =================
    for (int t = 0; t < NXY; t += 2) {
        mfma_phase(buf0, t);
        cvt_write(wB0, wB1, wB2, g0a, g0b, g1a, g1b, g2a, g2b, buf1);  // xy t+1
        load_q(t + 3, iB0, iB1, iB2, wB0, wB1, wB2);
        issue_gather(iA0, iA1, iA2);                                   // xy t+2
        __syncthreads();

        mfma_phase(buf1, t + 1);
        cvt_write(wA0, wA1, wA2, g0a, g0b, g1a, g1b, g2a, g2b, buf0);  // xy t+2
        load_q(t + 4, iA0, iA1, iA2, wA0, wA1, wA2);
        issue_gather(iB0, iB1, iB2);                                   // xy t+3
        __syncthreads();
    }

    // ================= epilogue: ReLU + store =================
    // D frag (16x16): row = mf*16 + 4*lg + r, col = wid*64 + nf*16 + l15
#pragma unroll
    for (int mf = 0; mf < 4; ++mf) {
        int row0 = k0 + mf * 16 + (lg << 2);
#pragma unroll
        for (int nf = 0; nf < 4; ++nf) {
            long col = (long)(wid << 6) + nf * 16 + l15;
            floatx4 d = acc[mf][nf];
#pragma unroll
            for (int r = 0; r < 4; ++r) {
                int row = row0 + r;
                if (row < NV) out[(long)row * N + col] = fmaxf(d[r], 0.f);
            }
        }
    }
}

extern "C" void kernel_launch(void* const* d_in, const int* in_sizes, int n_in,
                              void* d_out, int out_size, void* d_ws, size_t ws_size,
                              hipStream_t stream) {
    const float* mesh   = (const float*)d_in[0];
    const int*   bidx   = (const int*)d_in[1];
    const float* bw     = (const float*)d_in[2];
    const float* kern   = (const float*)d_in[3];
    const float* nw     = (const float*)d_in[4];
    const float* sw     = (const float*)d_in[5];
    const float* bias   = (const float*)d_in[6];
    const int*   deltap = (const int*)d_in[7];

    int N = out_size / NV;                       // 512 for delta=1
    unsigned short* w2 = (unsigned short*)d_ws;  // KDIM*N shorts x2 interleaved = 5.24 MB

    int total = KDIM * N;
    build_w2p_kernel<<<(total + 255) / 256, 256, 0, stream>>>(kern, nw, deltap, w2, N);

    int nblocks = (NV + 63) / 64;                // 782
    conv_mfma_kernel<<<nblocks, 512, 0, stream>>>(mesh, bidx, bw, w2,
                                                  sw, bias, (float*)d_out, N);
}